// Round 1
// baseline (6093.605 us; speedup 1.0000x reference)
//
#include <hip/hip_runtime.h>
#include <math.h>

#define BB 4
#define SS 2048
#define DD 1024
#define HH 16
#define DKK 64

// ---------------- GEMM: y[M,N] = x[M,K] @ W[N,K]^T + bias[N] ----------------
// BM=BN=64, BK=32, 256 threads, 4x4 micro-tile per thread.
__global__ __launch_bounds__(256) void gemm_xwt(
    const float* __restrict__ x, const float* __restrict__ w,
    const float* __restrict__ bias, float* __restrict__ y,
    int M, int N, int K) {
  __shared__ float As[64][33];
  __shared__ float Bs[64][33];
  const int tid = threadIdx.x;
  const int ty = tid >> 4;      // 0..15
  const int tx = tid & 15;      // 0..15
  const int brow = blockIdx.y * 64;
  const int bcol = blockIdx.x * 64;

  float acc[4][4] = {};

  for (int k0 = 0; k0 < K; k0 += 32) {
    // load 64x32 tiles of x and W (2048 elems each, 8 per thread)
#pragma unroll
    for (int i = 0; i < 8; ++i) {
      int idx = tid + i * 256;
      int r = idx >> 5;        // /32
      int c = idx & 31;
      As[r][c] = x[(size_t)(brow + r) * K + k0 + c];
      Bs[r][c] = w[(size_t)(bcol + r) * K + k0 + c];
    }
    __syncthreads();
#pragma unroll
    for (int kk = 0; kk < 32; ++kk) {
      float a[4], b[4];
#pragma unroll
      for (int i = 0; i < 4; ++i) a[i] = As[ty * 4 + i][kk];
#pragma unroll
      for (int j = 0; j < 4; ++j) b[j] = Bs[tx * 4 + j][kk];
#pragma unroll
      for (int i = 0; i < 4; ++i)
#pragma unroll
        for (int j = 0; j < 4; ++j) acc[i][j] += a[i] * b[j];
    }
    __syncthreads();
  }

#pragma unroll
  for (int i = 0; i < 4; ++i) {
    int row = brow + ty * 4 + i;
#pragma unroll
    for (int j = 0; j < 4; ++j) {
      int col = bcol + tx * 4 + j;
      y[(size_t)row * N + col] = acc[i][j] + bias[col];
    }
  }
}

// ---------------- Flash attention (causal), fp32 vector ALU ----------------
// One block per (b, h, q-tile of 64 rows). 256 threads, 4x4 micro-tile.
__global__ __launch_bounds__(256) void attn_fwd(
    const float* __restrict__ q, const float* __restrict__ k,
    const float* __restrict__ v, float* __restrict__ ctx) {
  __shared__ float Qs[64][65];
  __shared__ float Ks[64][65];
  __shared__ float Vs[64][65];
  __shared__ float Ps[64][65];

  const int bid = blockIdx.x;
  const int qt = bid & 31;           // S/64 = 32 q-tiles
  const int h  = (bid >> 5) & 15;
  const int b  = bid >> 9;

  const int tid = threadIdx.x;
  const int ty = tid >> 4;
  const int tx = tid & 15;

  const size_t base = (size_t)b * SS * DD + (size_t)h * DKK;
  const float* qbase = q + base + (size_t)(qt * 64) * DD;

  // load Q tile [64][64]
#pragma unroll
  for (int i = 0; i < 16; ++i) {
    int idx = tid + i * 256;
    int r = idx >> 6;
    int c = idx & 63;
    Qs[r][c] = qbase[(size_t)r * DD + c];
  }

  float m_run[4], l_run[4];
  float o[4][4] = {};
#pragma unroll
  for (int i = 0; i < 4; ++i) { m_run[i] = -INFINITY; l_run[i] = 0.0f; }

  const float scale = 0.125f;  // 1/sqrt(64)

  for (int kt = 0; kt <= qt; ++kt) {
    const float* kbase = k + base + (size_t)(kt * 64) * DD;
    const float* vbase = v + base + (size_t)(kt * 64) * DD;
    __syncthreads();   // protect Ks/Vs/Ps from previous iteration readers
#pragma unroll
    for (int i = 0; i < 16; ++i) {
      int idx = tid + i * 256;
      int r = idx >> 6;
      int c = idx & 63;
      Ks[r][c] = kbase[(size_t)r * DD + c];
      Vs[r][c] = vbase[(size_t)r * DD + c];
    }
    __syncthreads();

    // S = Q K^T  (per-thread 4x4 over 64-deep dot products)
    float s[4][4] = {};
#pragma unroll
    for (int d = 0; d < 64; ++d) {
      float a[4], bkk[4];
#pragma unroll
      for (int i = 0; i < 4; ++i) a[i] = Qs[ty * 4 + i][d];
#pragma unroll
      for (int j = 0; j < 4; ++j) bkk[j] = Ks[tx * 4 + j][d];
#pragma unroll
      for (int i = 0; i < 4; ++i)
#pragma unroll
        for (int j = 0; j < 4; ++j) s[i][j] += a[i] * bkk[j];
    }

    // scale + causal mask (only on diagonal tile)
    if (kt == qt) {
#pragma unroll
      for (int i = 0; i < 4; ++i) {
        int qi = ty * 4 + i;
#pragma unroll
        for (int j = 0; j < 4; ++j) {
          int ki = tx * 4 + j;
          s[i][j] = (ki <= qi) ? s[i][j] * scale : -1e30f;
        }
      }
    } else {
#pragma unroll
      for (int i = 0; i < 4; ++i)
#pragma unroll
        for (int j = 0; j < 4; ++j) s[i][j] *= scale;
    }

    // online softmax: per row (64 cols spread over 16 lanes with same ty)
    float p[4][4];
#pragma unroll
    for (int i = 0; i < 4; ++i) {
      float rm = fmaxf(fmaxf(s[i][0], s[i][1]), fmaxf(s[i][2], s[i][3]));
#pragma unroll
      for (int off = 8; off >= 1; off >>= 1)
        rm = fmaxf(rm, __shfl_xor(rm, off));
      float m_new = fmaxf(m_run[i], rm);
      float factor = expf(m_run[i] - m_new);
      float rs = 0.0f;
#pragma unroll
      for (int j = 0; j < 4; ++j) {
        p[i][j] = expf(s[i][j] - m_new);
        rs += p[i][j];
      }
#pragma unroll
      for (int off = 8; off >= 1; off >>= 1)
        rs += __shfl_xor(rs, off);
      l_run[i] = l_run[i] * factor + rs;
      m_run[i] = m_new;
#pragma unroll
      for (int j = 0; j < 4; ++j) o[i][j] *= factor;
    }

    // share P through LDS, then O += P @ V
    __syncthreads();  // Ps reuse guard (also separates from Ks/Vs loads)
#pragma unroll
    for (int i = 0; i < 4; ++i)
#pragma unroll
      for (int j = 0; j < 4; ++j) Ps[ty * 4 + i][tx * 4 + j] = p[i][j];
    __syncthreads();

#pragma unroll
    for (int kc = 0; kc < 64; ++kc) {
      float a[4], bkk[4];
#pragma unroll
      for (int i = 0; i < 4; ++i) a[i] = Ps[ty * 4 + i][kc];
#pragma unroll
      for (int j = 0; j < 4; ++j) bkk[j] = Vs[kc][tx * 4 + j];
#pragma unroll
      for (int i = 0; i < 4; ++i)
#pragma unroll
        for (int j = 0; j < 4; ++j) o[i][j] += a[i] * bkk[j];
    }
  }

  // epilogue: divide by l, write ctx (in-place over q is safe: this block is
  // the only reader of its q tile and it already consumed it)
  float* cbase = ctx + base + (size_t)(qt * 64) * DD;
#pragma unroll
  for (int i = 0; i < 4; ++i) {
    float inv = 1.0f / l_run[i];
    int r = ty * 4 + i;
#pragma unroll
    for (int j = 0; j < 4; ++j) {
      cbase[(size_t)r * DD + tx * 4 + j] = o[i][j] * inv;
    }
  }
}

extern "C" void kernel_launch(void* const* d_in, const int* in_sizes, int n_in,
                              void* d_out, int out_size, void* d_ws, size_t ws_size,
                              hipStream_t stream) {
  const float* query = (const float*)d_in[0];
  const float* key_  = (const float*)d_in[1];
  const float* value = (const float*)d_in[2];
  const float* Wq = (const float*)d_in[3];
  const float* bq = (const float*)d_in[4];
  const float* Wk = (const float*)d_in[5];
  const float* bk = (const float*)d_in[6];
  const float* Wv = (const float*)d_in[7];
  const float* bv = (const float*)d_in[8];
  const float* Wo = (const float*)d_in[9];
  const float* bo = (const float*)d_in[10];
  // d_in[11] = mask: known-causal tril, handled analytically.
  float* out = (float*)d_out;

  const int M = BB * SS;   // 8192
  const int N = DD;        // 1024
  const int K = DD;        // 1024

  float* qbuf = (float*)d_ws;                       // B*S*D floats
  float* kbuf = qbuf + (size_t)BB * SS * DD;
  float* vbuf = kbuf + (size_t)BB * SS * DD;

  dim3 gblk(256);
  dim3 ggrid(N / 64, M / 64);

  hipLaunchKernelGGL(gemm_xwt, ggrid, gblk, 0, stream, query, Wq, bq, qbuf, M, N, K);
  hipLaunchKernelGGL(gemm_xwt, ggrid, gblk, 0, stream, key_,  Wk, bk, kbuf, M, N, K);
  hipLaunchKernelGGL(gemm_xwt, ggrid, gblk, 0, stream, value, Wv, bv, vbuf, M, N, K);

  dim3 ablk(256);
  dim3 agrid(BB * HH * (SS / 64));   // 2048 blocks
  hipLaunchKernelGGL(attn_fwd, agrid, ablk, 0, stream, qbuf, kbuf, vbuf, qbuf);

  hipLaunchKernelGGL(gemm_xwt, ggrid, gblk, 0, stream, qbuf, Wo, bo, out, M, N, K);
}

// Round 3
// 703.425 us; speedup vs baseline: 8.6628x; 8.6628x over previous
//
#include <hip/hip_runtime.h>
#include <math.h>

#define BB 4
#define SS 2048
#define DD 1024
#define HH 16
#define DKK 64

typedef __attribute__((ext_vector_type(8))) short bf16x8;
typedef __attribute__((ext_vector_type(4))) float f32x4;

#define GLOAD16(g, l)                                                        \
  __builtin_amdgcn_global_load_lds(                                          \
      (const __attribute__((address_space(1))) void*)(g),                    \
      (__attribute__((address_space(3))) void*)(l), 16, 0, 0)

static __device__ __forceinline__ unsigned short f2b(float f) {
  union { float f; unsigned u; } x; x.f = f;
  unsigned r = x.u + 0x7fffu + ((x.u >> 16) & 1u);
  return (unsigned short)(r >> 16);
}

// ---------------- fp32 -> bf16 conversion (vectorized) ----------------
__global__ __launch_bounds__(256) void conv_f2b(const float* __restrict__ in,
                                                unsigned short* __restrict__ out,
                                                int n) {
  int i = (blockIdx.x * 256 + threadIdx.x) * 4;
  const int stride = gridDim.x * 256 * 4;
  for (; i < n; i += stride) {
    float4 v = *(const float4*)(in + i);
    ushort4 o;
    o.x = f2b(v.x); o.y = f2b(v.y); o.z = f2b(v.z); o.w = f2b(v.w);
    *(ushort4*)(out + i) = o;
  }
}

// ---------------- GEMM: C[M,N] = A[M,K] @ W[N,K]^T + bias ----------------
// 128x128 tile, BK=32, 256 threads (4 waves, 2x2), 16 MFMA/wave/K-step.
template <typename OUT>
__global__ __launch_bounds__(256) void gemm_mfma(
    const unsigned short* __restrict__ A,   // [M][K] bf16
    const unsigned short* __restrict__ B,   // [N][K] bf16 (= B^T layout)
    const float* __restrict__ bias,
    OUT* __restrict__ C, int M, int N, int K) {
  __shared__ unsigned short As[128 * 32];
  __shared__ unsigned short Bs[128 * 32];
  const int tid = threadIdx.x;
  const int lane = tid & 63;
  const int w = tid >> 6;            // 0..3
  const int wr = w >> 1, wc = w & 1; // wave grid 2x2, 64x64 each
  const int brow = blockIdx.y * 128, bcol = blockIdx.x * 128;

  f32x4 acc[4][4] = {};

  // staging: chunk = 16 rows x 32 cols (1 KiB). wave w does chunks w and w+4.
  const int srow = lane >> 2;           // 0..15
  const int scol = (lane & 3) * 8;      // 0,8,16,24
  const unsigned short* Ag0 = A + (size_t)(brow + w * 16 + srow) * K + scol;
  const unsigned short* Ag1 = A + (size_t)(brow + 64 + w * 16 + srow) * K + scol;
  const unsigned short* Bg0 = B + (size_t)(bcol + w * 16 + srow) * K + scol;
  const unsigned short* Bg1 = B + (size_t)(bcol + 64 + w * 16 + srow) * K + scol;
  unsigned short* As0 = &As[(w * 16) * 32];
  unsigned short* As1 = &As[(64 + w * 16) * 32];
  unsigned short* Bs0 = &Bs[(w * 16) * 32];
  unsigned short* Bs1 = &Bs[(64 + w * 16) * 32];

  const int fr = lane & 15;        // fragment row/col
  const int k8 = (lane >> 4) * 8;  // fragment k offset

  for (int k0 = 0; k0 < K; k0 += 32) {
    GLOAD16(Ag0 + k0, As0);
    GLOAD16(Ag1 + k0, As1);
    GLOAD16(Bg0 + k0, Bs0);
    GLOAD16(Bg1 + k0, Bs1);
    __syncthreads();   // drains vmcnt: tiles resident

    bf16x8 a[4], bb[4];
#pragma unroll
    for (int m = 0; m < 4; ++m)
      a[m] = *(const bf16x8*)&As[(wr * 64 + m * 16 + fr) * 32 + k8];
#pragma unroll
    for (int n = 0; n < 4; ++n)
      bb[n] = *(const bf16x8*)&Bs[(wc * 64 + n * 16 + fr) * 32 + k8];
#pragma unroll
    for (int m = 0; m < 4; ++m)
#pragma unroll
      for (int n = 0; n < 4; ++n)
        acc[m][n] = __builtin_amdgcn_mfma_f32_16x16x32_bf16(a[m], bb[n], acc[m][n], 0, 0, 0);
    __syncthreads();   // compute done before next staging lands
  }

#pragma unroll
  for (int m = 0; m < 4; ++m) {
    int row = brow + wr * 64 + m * 16 + (lane >> 4) * 4;
#pragma unroll
    for (int n = 0; n < 4; ++n) {
      int col = bcol + wc * 64 + n * 16 + fr;
      float bv = bias[col];
#pragma unroll
      for (int j = 0; j < 4; ++j) {
        float vv = acc[m][n][j] + bv;
        if constexpr (sizeof(OUT) == 2)
          ((unsigned short*)C)[(size_t)(row + j) * N + col] = f2b(vv);
        else
          ((float*)C)[(size_t)(row + j) * N + col] = vv;
      }
    }
  }
}

// ---------------- Flash attention (causal), bf16 MFMA ----------------
// 1 block / (b,h,64-row q-tile). 4 waves x 16 q-rows. KVBLK=64.
__global__ __launch_bounds__(256) void attn_mfma(
    const unsigned short* __restrict__ q, const unsigned short* __restrict__ k,
    const unsigned short* __restrict__ v, unsigned short* __restrict__ ctx) {
  __shared__ unsigned short Ks[64 * 64];      // row-major [kv][d]
  __shared__ unsigned short Vt[64 * 64];      // transposed [d][kv]
  __shared__ unsigned short Ps[4][16 * 64];   // per-wave P tile

  const int bid = blockIdx.x;
  const int qt = bid & 31;
  const int h = (bid >> 5) & 15;
  const int b = bid >> 9;
  const int tid = threadIdx.x;
  const int lane = tid & 63;
  const int w = tid >> 6;

  const size_t bS = (size_t)b * SS;
  const int q0 = qt * 64 + w * 16;   // wave's first q row
  const int fr = lane & 15;
  const int k8 = (lane >> 4) * 8;

  // Q fragments in registers (A-operand layout: row=lane&15, k=(lane>>4)*8+b)
  const unsigned short* qrow = q + (bS + q0 + fr) * DD + h * 64;
  bf16x8 aq0 = *(const bf16x8*)(qrow + k8);
  bf16x8 aq1 = *(const bf16x8*)(qrow + 32 + k8);

  f32x4 oc[4] = {};
  float m_run[4], l_run[4];
#pragma unroll
  for (int j = 0; j < 4; ++j) { m_run[j] = -INFINITY; l_run[j] = 0.0f; }

  // K staging via global_load_lds: chunk = 8 rows x 128B; wave w: chunks w, w+4
  const unsigned short* Kg0 =
      k + (bS + w * 8 + (lane >> 3)) * DD + h * 64 + (lane & 7) * 8;
  const unsigned short* Kg1 =
      k + (bS + 32 + w * 8 + (lane >> 3)) * DD + h * 64 + (lane & 7) * 8;

  for (int kt = 0; kt <= qt; ++kt) {
    __syncthreads();  // previous iteration's readers done
    const size_t koff = (size_t)(kt * 64) * DD;
    GLOAD16(Kg0 + koff, &Ks[(w * 8) * 64]);
    GLOAD16(Kg1 + koff, &Ks[(32 + w * 8) * 64]);
    // V staged transposed (b_frag for PV must be contiguous in kv)
#pragma unroll
    for (int r = 0; r < 2; ++r) {
      int idx = r * 256 + tid;     // 0..511
      int kv = idx >> 3;           // 0..63
      int d0 = (idx & 7) * 8;
      bf16x8 vv = *(const bf16x8*)(v + (bS + kt * 64 + kv) * DD + h * 64 + d0);
#pragma unroll
      for (int j2 = 0; j2 < 8; ++j2)
        Vt[(d0 + j2) * 64 + kv] = ((const unsigned short*)&vv)[j2];
    }
    __syncthreads();  // tiles resident

    // S = Q K^T : 8 MFMAs -> sc[n] covers cols n*16..n*16+15
    f32x4 sc[4] = {};
#pragma unroll
    for (int n = 0; n < 4; ++n) {
      bf16x8 bk0 = *(const bf16x8*)&Ks[(n * 16 + fr) * 64 + k8];
      bf16x8 bk1 = *(const bf16x8*)&Ks[(n * 16 + fr) * 64 + 32 + k8];
      sc[n] = __builtin_amdgcn_mfma_f32_16x16x32_bf16(aq0, bk0, sc[n], 0, 0, 0);
      sc[n] = __builtin_amdgcn_mfma_f32_16x16x32_bf16(aq1, bk1, sc[n], 0, 0, 0);
    }

    // scale + causal mask (only diagonal tile has masked elems: kt==qt)
    if (kt == qt) {
#pragma unroll
      for (int n = 0; n < 4; ++n) {
        int col = n * 16 + fr;
#pragma unroll
        for (int j = 0; j < 4; ++j) {
          int row = w * 16 + (lane >> 4) * 4 + j;
          sc[n][j] = (col <= row) ? sc[n][j] * 0.125f : -1e30f;
        }
      }
    } else {
#pragma unroll
      for (int n = 0; n < 4; ++n)
#pragma unroll
        for (int j = 0; j < 4; ++j) sc[n][j] *= 0.125f;
    }

    // online softmax per row j; row spread over 4 in-lane frags x 16 lanes
#pragma unroll
    for (int j = 0; j < 4; ++j) {
      float rm = fmaxf(fmaxf(sc[0][j], sc[1][j]), fmaxf(sc[2][j], sc[3][j]));
#pragma unroll
      for (int off = 8; off >= 1; off >>= 1) rm = fmaxf(rm, __shfl_xor(rm, off));
      float m_new = fmaxf(m_run[j], rm);
      float factor = __expf(m_run[j] - m_new);
      float pj[4], rs = 0.0f;
#pragma unroll
      for (int n = 0; n < 4; ++n) { pj[n] = __expf(sc[n][j] - m_new); rs += pj[n]; }
#pragma unroll
      for (int off = 8; off >= 1; off >>= 1) rs += __shfl_xor(rs, off);
      l_run[j] = l_run[j] * factor + rs;
      m_run[j] = m_new;
#pragma unroll
      for (int n = 0; n < 4; ++n) oc[n][j] *= factor;
      // P into per-wave LDS (C-layout -> A-layout transpose bounce)
      int prow = (lane >> 4) * 4 + j;
#pragma unroll
      for (int n = 0; n < 4; ++n) Ps[w][prow * 64 + n * 16 + fr] = f2b(pj[n]);
    }

    asm volatile("s_waitcnt lgkmcnt(0)" ::: "memory");  // wave-local Ps ready

    // O += P @ V
#pragma unroll
    for (int s = 0; s < 2; ++s) {
      bf16x8 pa = *(const bf16x8*)&Ps[w][fr * 64 + s * 32 + k8];
#pragma unroll
      for (int n = 0; n < 4; ++n) {
        bf16x8 bv = *(const bf16x8*)&Vt[(n * 16 + fr) * 64 + s * 32 + k8];
        oc[n] = __builtin_amdgcn_mfma_f32_16x16x32_bf16(pa, bv, oc[n], 0, 0, 0);
      }
    }
  }

  // epilogue: O / l -> bf16 ctx
  unsigned short* crow = ctx + (bS + q0) * DD + h * 64;
#pragma unroll
  for (int j = 0; j < 4; ++j) {
    float inv = 1.0f / l_run[j];
    int rr = (lane >> 4) * 4 + j;
#pragma unroll
    for (int n = 0; n < 4; ++n)
      crow[(size_t)rr * DD + n * 16 + fr] = f2b(oc[n][j] * inv);
  }
}

extern "C" void kernel_launch(void* const* d_in, const int* in_sizes, int n_in,
                              void* d_out, int out_size, void* d_ws, size_t ws_size,
                              hipStream_t stream) {
  const float* query = (const float*)d_in[0];
  const float* key_  = (const float*)d_in[1];
  const float* value = (const float*)d_in[2];
  const float* Wq = (const float*)d_in[3];
  const float* bq = (const float*)d_in[4];
  const float* Wk = (const float*)d_in[5];
  const float* bk = (const float*)d_in[6];
  const float* Wv = (const float*)d_in[7];
  const float* bv = (const float*)d_in[8];
  const float* Wo = (const float*)d_in[9];
  const float* bo = (const float*)d_in[10];
  float* out = (float*)d_out;

  const int M = BB * SS;  // 8192
  const int N = DD;       // 1024
  const int K = DD;       // 1024
  const size_t NX = (size_t)M * DD;   // 8.4M elems
  const size_t NW = (size_t)DD * DD;  // 1M elems

  unsigned short* Xb = (unsigned short*)d_ws;     // converted input / ctx (reused)
  unsigned short* W0 = Xb + NX;
  unsigned short* W1 = W0 + NW;
  unsigned short* W2 = W1 + NW;
  unsigned short* W3 = W2 + NW;
  unsigned short* qb = W3 + NW;
  unsigned short* kb = qb + NX;
  unsigned short* vb = kb + NX;

  dim3 cblk(256), cgrid(2048);
  dim3 gblk(256), ggrid(N / 128, M / 128);

  // weights once
  hipLaunchKernelGGL(conv_f2b, dim3(256), cblk, 0, stream, Wq, W0, (int)NW);
  hipLaunchKernelGGL(conv_f2b, dim3(256), cblk, 0, stream, Wk, W1, (int)NW);
  hipLaunchKernelGGL(conv_f2b, dim3(256), cblk, 0, stream, Wv, W2, (int)NW);
  hipLaunchKernelGGL(conv_f2b, dim3(256), cblk, 0, stream, Wo, W3, (int)NW);

  // q = query @ Wq^T
  hipLaunchKernelGGL(conv_f2b, cgrid, cblk, 0, stream, query, Xb, (int)NX);
  hipLaunchKernelGGL(gemm_mfma<unsigned short>, ggrid, gblk, 0, stream,
                     Xb, W0, bq, qb, M, N, K);
  // k
  hipLaunchKernelGGL(conv_f2b, cgrid, cblk, 0, stream, key_, Xb, (int)NX);
  hipLaunchKernelGGL(gemm_mfma<unsigned short>, ggrid, gblk, 0, stream,
                     Xb, W1, bk, kb, M, N, K);
  // v
  hipLaunchKernelGGL(conv_f2b, cgrid, cblk, 0, stream, value, Xb, (int)NX);
  hipLaunchKernelGGL(gemm_mfma<unsigned short>, ggrid, gblk, 0, stream,
                     Xb, W2, bv, vb, M, N, K);

  // attention -> ctx (bf16) into Xb
  hipLaunchKernelGGL(attn_mfma, dim3(BB * HH * (SS / 64)), dim3(256), 0, stream,
                     qb, kb, vb, Xb);

  // out = ctx @ Wo^T + bo  (fp32 out)
  hipLaunchKernelGGL(gemm_mfma<float>, ggrid, gblk, 0, stream,
                     Xb, W3, bo, out, M, N, K);
}

// Round 4
// 540.987 us; speedup vs baseline: 11.2639x; 1.3003x over previous
//
#include <hip/hip_runtime.h>
#include <math.h>

#define BB 4
#define SS 2048
#define DD 1024
#define HH 16

typedef __attribute__((ext_vector_type(8))) short bf16x8;
typedef __attribute__((ext_vector_type(4))) float f32x4;

#define GLOAD16(g, l)                                                        \
  __builtin_amdgcn_global_load_lds(                                          \
      (const __attribute__((address_space(1))) void*)(g),                    \
      (__attribute__((address_space(3))) void*)(l), 16, 0, 0)

static __device__ __forceinline__ unsigned short f2b(float f) {
  union { float f; unsigned u; } x; x.f = f;
  unsigned r = x.u + 0x7fffu + ((x.u >> 16) & 1u);
  return (unsigned short)(r >> 16);
}

// Swizzled short-offset for 64-short (128B) rows: XOR the 16B-chunk index
// with ((row ^ row>>3) & 7). Bijective within each row; spreads both
// stride-1-row readers and stride-8-row writers across banks.
static __device__ __forceinline__ int swz8(int row, int c0) {
  return row * 64 + (((c0 ^ (row ^ (row >> 3))) & 7) * 8);
}

// ---------------- fp32 -> bf16 conversion (vectorized) ----------------
__global__ __launch_bounds__(256) void conv_f2b(const float* __restrict__ in,
                                                unsigned short* __restrict__ out,
                                                int n) {
  int i = (blockIdx.x * 256 + threadIdx.x) * 4;
  const int stride = gridDim.x * 256 * 4;
  for (; i < n; i += stride) {
    float4 v = *(const float4*)(in + i);
    ushort4 o;
    o.x = f2b(v.x); o.y = f2b(v.y); o.z = f2b(v.z); o.w = f2b(v.w);
    *(ushort4*)(out + i) = o;
  }
}

// ---------------- GEMM: C[M,N] = A[M,K] @ W[N,K]^T + bias ----------------
// 128x128 tile, BK=32, 256 threads (4 waves, 2x2). XCD-chunked bid swizzle.
template <typename OUT>
__global__ __launch_bounds__(256) void gemm_mfma(
    const unsigned short* __restrict__ A,   // [M][K] bf16
    const unsigned short* __restrict__ B,   // [N][K] bf16 (= B^T layout)
    const float* __restrict__ bias,
    OUT* __restrict__ C, int M, int N, int K) {
  __shared__ unsigned short As[128 * 32];
  __shared__ unsigned short Bs[128 * 32];
  const int tid = threadIdx.x;
  const int lane = tid & 63;
  const int w = tid >> 6;            // 0..3
  const int wr = w >> 1, wc = w & 1; // wave grid 2x2, 64x64 each
  // XCD-chunked swizzle: 512 blocks, 8 XCDs -> 64 consecutive works per XCD
  // (work = y*8+x so one XCD owns whole A-row-panels).
  const int lin = blockIdx.y * gridDim.x + blockIdx.x;
  const int nwg = gridDim.x * gridDim.y;
  const int cpx = nwg >> 3;
  const int swz = (lin & 7) * cpx + (lin >> 3);
  const int brow = (swz >> 3) * 128, bcol = (swz & 7) * 128;

  f32x4 acc[4][4] = {};

  const int srow = lane >> 2;           // 0..15
  const int scol = (lane & 3) * 8;      // 0,8,16,24
  const unsigned short* Ag0 = A + (size_t)(brow + w * 16 + srow) * K + scol;
  const unsigned short* Ag1 = A + (size_t)(brow + 64 + w * 16 + srow) * K + scol;
  const unsigned short* Bg0 = B + (size_t)(bcol + w * 16 + srow) * K + scol;
  const unsigned short* Bg1 = B + (size_t)(bcol + 64 + w * 16 + srow) * K + scol;
  unsigned short* As0 = &As[(w * 16) * 32];
  unsigned short* As1 = &As[(64 + w * 16) * 32];
  unsigned short* Bs0 = &Bs[(w * 16) * 32];
  unsigned short* Bs1 = &Bs[(64 + w * 16) * 32];

  const int fr = lane & 15;        // fragment row/col
  const int k8 = (lane >> 4) * 8;  // fragment k offset

  for (int k0 = 0; k0 < K; k0 += 32) {
    GLOAD16(Ag0 + k0, As0);
    GLOAD16(Ag1 + k0, As1);
    GLOAD16(Bg0 + k0, Bs0);
    GLOAD16(Bg1 + k0, Bs1);
    __syncthreads();   // drains vmcnt: tiles resident

    bf16x8 a[4], bb[4];
#pragma unroll
    for (int m = 0; m < 4; ++m)
      a[m] = *(const bf16x8*)&As[(wr * 64 + m * 16 + fr) * 32 + k8];
#pragma unroll
    for (int n = 0; n < 4; ++n)
      bb[n] = *(const bf16x8*)&Bs[(wc * 64 + n * 16 + fr) * 32 + k8];
#pragma unroll
    for (int m = 0; m < 4; ++m)
#pragma unroll
      for (int n = 0; n < 4; ++n)
        acc[m][n] = __builtin_amdgcn_mfma_f32_16x16x32_bf16(a[m], bb[n], acc[m][n], 0, 0, 0);
    __syncthreads();   // compute done before next staging lands
  }

#pragma unroll
  for (int m = 0; m < 4; ++m) {
    int row = brow + wr * 64 + m * 16 + (lane >> 4) * 4;
#pragma unroll
    for (int n = 0; n < 4; ++n) {
      int col = bcol + wc * 64 + n * 16 + fr;
      float bv = bias[col];
#pragma unroll
      for (int j = 0; j < 4; ++j) {
        float vv = acc[m][n][j] + bv;
        if constexpr (sizeof(OUT) == 2)
          ((unsigned short*)C)[(size_t)(row + j) * N + col] = f2b(vv);
        else
          ((float*)C)[(size_t)(row + j) * N + col] = vv;
      }
    }
  }
}

// ---------------- Flash attention (causal), bf16 MFMA, swizzled LDS -------
// 1 block / (b,h,128-row q-tile). 4 waves x 32 q-rows. KVBLK=64.
__global__ __launch_bounds__(256) void attn_mfma(
    const unsigned short* __restrict__ q, const unsigned short* __restrict__ k,
    const unsigned short* __restrict__ v, unsigned short* __restrict__ ctx) {
  __shared__ unsigned short Ks[64 * 64];      // [kv][d] swizzled
  __shared__ unsigned short Vt[64 * 64];      // [d][kv] swizzled
  __shared__ unsigned short Ps[4][32 * 64];   // per-wave [qrow][kv] swizzled

  // XCD-chunked swizzle: 1024 blocks -> 128/XCD; one XCD owns whole (b,h)
  // groups so K/V tiles are XCD-L2-local.
  const int orig = blockIdx.x;
  const int sbid = (orig & 7) * 128 + (orig >> 3);
  const int qt = sbid & 15;          // S/128 = 16 q-tiles
  const int h = (sbid >> 4) & 15;
  const int b = sbid >> 8;

  const int tid = threadIdx.x;
  const int lane = tid & 63;
  const int w = tid >> 6;

  const size_t bS = (size_t)b * SS;
  const int q0w = qt * 128 + w * 32;   // wave's first q row
  const int fr = lane & 15;
  const int qw = lane >> 4;            // quarter-wave 0..3
  const int k8 = qw * 8;

  // Q fragments in registers: aq[h2][s] covers rows q0w+h2*16+fr, d=s*32+k8..
  bf16x8 aq[2][2];
#pragma unroll
  for (int h2 = 0; h2 < 2; ++h2) {
    const unsigned short* qrow = q + (bS + q0w + h2 * 16 + fr) * DD + h * 64;
#pragma unroll
    for (int s = 0; s < 2; ++s)
      aq[h2][s] = *(const bf16x8*)(qrow + s * 32 + k8);
  }

  f32x4 oc[2][4] = {};
  float m_run[2][4], l_run[2][4];
#pragma unroll
  for (int h2 = 0; h2 < 2; ++h2)
#pragma unroll
    for (int j = 0; j < 4; ++j) { m_run[h2][j] = -INFINITY; l_run[h2][j] = 0.0f; }

  // K staging (gload_lds): linear LDS dest + pre-swizzled global source.
  const int r0 = w * 8 + (lane >> 3);
  const int g0 = ((lane & 7) ^ (r0 ^ (r0 >> 3))) & 7;
  const int r1 = 32 + w * 8 + (lane >> 3);
  const int g1 = ((lane & 7) ^ (r1 ^ (r1 >> 3))) & 7;
  const unsigned short* Kg0 = k + (bS + r0) * DD + h * 64 + g0 * 8;
  const unsigned short* Kg1 = k + (bS + r1) * DD + h * 64 + g1 * 8;
  unsigned short* KsD0 = &Ks[(w * 8) * 64];
  unsigned short* KsD1 = &Ks[(32 + w * 8) * 64];

  const float SCL = 0.1803368801f;  // 0.125 * log2(e): softmax in exp2 domain

  const int nkt = qt * 2 + 2;
  for (int kt = 0; kt < nkt; ++kt) {
    __syncthreads();  // previous iteration's readers done
    const size_t koff = (size_t)(kt * 64) * DD;
    GLOAD16(Kg0 + koff, KsD0);
    GLOAD16(Kg1 + koff, KsD1);
    // V transpose staging: vector load + swizzled scalar stores
#pragma unroll
    for (int r = 0; r < 2; ++r) {
      int idx = r * 256 + tid;     // 0..511
      int kv = idx >> 3;           // 0..63
      int d0 = (idx & 7) * 8;
      bf16x8 vv = *(const bf16x8*)(v + (bS + kt * 64 + kv) * DD + h * 64 + d0);
      int ch = kv >> 3, cl = kv & 7;
#pragma unroll
      for (int j2 = 0; j2 < 8; ++j2)
        Vt[swz8(d0 + j2, ch) + cl] = ((const unsigned short*)&vv)[j2];
    }
    __syncthreads();  // tiles resident (vmcnt+lgkm drained by barrier)

    // S = Q K^T : 16 MFMAs (shared bk across h2)
    f32x4 sc[2][4] = {};
    __builtin_amdgcn_s_setprio(1);
#pragma unroll
    for (int n = 0; n < 4; ++n) {
      int row = n * 16 + fr;
      bf16x8 bk0 = *(const bf16x8*)&Ks[swz8(row, qw)];
      bf16x8 bk1 = *(const bf16x8*)&Ks[swz8(row, 4 + qw)];
#pragma unroll
      for (int h2 = 0; h2 < 2; ++h2) {
        sc[h2][n] = __builtin_amdgcn_mfma_f32_16x16x32_bf16(aq[h2][0], bk0, sc[h2][n], 0, 0, 0);
        sc[h2][n] = __builtin_amdgcn_mfma_f32_16x16x32_bf16(aq[h2][1], bk1, sc[h2][n], 0, 0, 0);
      }
    }
    __builtin_amdgcn_s_setprio(0);

    // scale into exp2 domain + causal mask (diag band only)
    const bool diag = (kt * 64 + 63 > q0w);
#pragma unroll
    for (int h2 = 0; h2 < 2; ++h2)
#pragma unroll
      for (int n = 0; n < 4; ++n)
#pragma unroll
        for (int j = 0; j < 4; ++j) {
          float x = sc[h2][n][j] * SCL;
          if (diag) {
            int rowg = q0w + h2 * 16 + qw * 4 + j;
            int colg = kt * 64 + n * 16 + fr;
            x = (colg <= rowg) ? x : -1e30f;
          }
          sc[h2][n][j] = x;
        }

    // online softmax (exp2 domain); rows live in quarter-wave (16-lane) groups
#pragma unroll
    for (int h2 = 0; h2 < 2; ++h2) {
#pragma unroll
      for (int j = 0; j < 4; ++j) {
        float rm = fmaxf(fmaxf(sc[h2][0][j], sc[h2][1][j]),
                         fmaxf(sc[h2][2][j], sc[h2][3][j]));
#pragma unroll
        for (int off = 8; off >= 1; off >>= 1) rm = fmaxf(rm, __shfl_xor(rm, off));
        float mo = m_run[h2][j];
        float mn = fmaxf(mo, rm);
        float fac = exp2f(mo - mn);
        float p[4], rs = 0.0f;
#pragma unroll
        for (int n = 0; n < 4; ++n) { p[n] = exp2f(sc[h2][n][j] - mn); rs += p[n]; }
#pragma unroll
        for (int off = 8; off >= 1; off >>= 1) rs += __shfl_xor(rs, off);
        l_run[h2][j] = l_run[h2][j] * fac + rs;
        m_run[h2][j] = mn;
#pragma unroll
        for (int n = 0; n < 4; ++n) oc[h2][n][j] *= fac;
        int prow = h2 * 16 + qw * 4 + j;
#pragma unroll
        for (int n = 0; n < 4; ++n)
          Ps[w][swz8(prow, n * 2 + (fr >> 3)) + (fr & 7)] = f2b(p[n]);
      }
    }

    asm volatile("s_waitcnt lgkmcnt(0)" ::: "memory");  // wave-local Ps ready

    // O += P @ V : 16 MFMAs (shared bv across h2)
    __builtin_amdgcn_s_setprio(1);
#pragma unroll
    for (int s = 0; s < 2; ++s) {
      bf16x8 pa0 = *(const bf16x8*)&Ps[w][swz8(fr, s * 4 + qw)];
      bf16x8 pa1 = *(const bf16x8*)&Ps[w][swz8(16 + fr, s * 4 + qw)];
#pragma unroll
      for (int n = 0; n < 4; ++n) {
        bf16x8 bv = *(const bf16x8*)&Vt[swz8(n * 16 + fr, s * 4 + qw)];
        oc[0][n] = __builtin_amdgcn_mfma_f32_16x16x32_bf16(pa0, bv, oc[0][n], 0, 0, 0);
        oc[1][n] = __builtin_amdgcn_mfma_f32_16x16x32_bf16(pa1, bv, oc[1][n], 0, 0, 0);
      }
    }
    __builtin_amdgcn_s_setprio(0);
  }

  // epilogue: O / l -> bf16 ctx
#pragma unroll
  for (int h2 = 0; h2 < 2; ++h2)
#pragma unroll
    for (int j = 0; j < 4; ++j) {
      float inv = 1.0f / l_run[h2][j];
      int row = q0w + h2 * 16 + qw * 4 + j;
      unsigned short* crow = ctx + (bS + row) * DD + h * 64;
#pragma unroll
      for (int n = 0; n < 4; ++n)
        crow[n * 16 + fr] = f2b(oc[h2][n][j] * inv);
    }
}

extern "C" void kernel_launch(void* const* d_in, const int* in_sizes, int n_in,
                              void* d_out, int out_size, void* d_ws, size_t ws_size,
                              hipStream_t stream) {
  const float* query = (const float*)d_in[0];
  const float* key_  = (const float*)d_in[1];
  const float* value = (const float*)d_in[2];
  const float* Wq = (const float*)d_in[3];
  const float* bq = (const float*)d_in[4];
  const float* Wk = (const float*)d_in[5];
  const float* bk = (const float*)d_in[6];
  const float* Wv = (const float*)d_in[7];
  const float* bv = (const float*)d_in[8];
  const float* Wo = (const float*)d_in[9];
  const float* bo = (const float*)d_in[10];
  float* out = (float*)d_out;

  const int M = BB * SS;  // 8192
  const int N = DD;       // 1024
  const int K = DD;       // 1024
  const size_t NX = (size_t)M * DD;   // 8.4M elems
  const size_t NW = (size_t)DD * DD;  // 1M elems

  unsigned short* Xb = (unsigned short*)d_ws;     // converted input / ctx (reused)
  unsigned short* W0 = Xb + NX;
  unsigned short* W1 = W0 + NW;
  unsigned short* W2 = W1 + NW;
  unsigned short* W3 = W2 + NW;
  unsigned short* qb = W3 + NW;
  unsigned short* kb = qb + NX;
  unsigned short* vb = kb + NX;

  dim3 cblk(256), cgrid(2048);
  dim3 gblk(256), ggrid(N / 128, M / 128);

  // weights once
  hipLaunchKernelGGL(conv_f2b, dim3(256), cblk, 0, stream, Wq, W0, (int)NW);
  hipLaunchKernelGGL(conv_f2b, dim3(256), cblk, 0, stream, Wk, W1, (int)NW);
  hipLaunchKernelGGL(conv_f2b, dim3(256), cblk, 0, stream, Wv, W2, (int)NW);
  hipLaunchKernelGGL(conv_f2b, dim3(256), cblk, 0, stream, Wo, W3, (int)NW);

  // q = query @ Wq^T
  hipLaunchKernelGGL(conv_f2b, cgrid, cblk, 0, stream, query, Xb, (int)NX);
  hipLaunchKernelGGL(gemm_mfma<unsigned short>, ggrid, gblk, 0, stream,
                     Xb, W0, bq, qb, M, N, K);
  // k
  hipLaunchKernelGGL(conv_f2b, cgrid, cblk, 0, stream, key_, Xb, (int)NX);
  hipLaunchKernelGGL(gemm_mfma<unsigned short>, ggrid, gblk, 0, stream,
                     Xb, W1, bk, kb, M, N, K);
  // v
  hipLaunchKernelGGL(conv_f2b, cgrid, cblk, 0, stream, value, Xb, (int)NX);
  hipLaunchKernelGGL(gemm_mfma<unsigned short>, ggrid, gblk, 0, stream,
                     Xb, W2, bv, vb, M, N, K);

  // attention -> ctx (bf16) into Xb
  hipLaunchKernelGGL(attn_mfma, dim3(BB * HH * (SS / 128)), dim3(256), 0, stream,
                     qb, kb, vb, Xb);

  // out = ctx @ Wo^T + bo  (fp32 out)
  hipLaunchKernelGGL(gemm_mfma<float>, ggrid, gblk, 0, stream,
                     Xb, W3, bo, out, M, N, K);
}

// Round 7
// 518.683 us; speedup vs baseline: 11.7482x; 1.0430x over previous
//
#include <hip/hip_runtime.h>
#include <math.h>

#define BB 4
#define SS 2048
#define DD 1024
#define HH 16

typedef __attribute__((ext_vector_type(8))) short bf16x8;
typedef __attribute__((ext_vector_type(4))) float f32x4;

#define GLOAD16(g, l)                                                        \
  __builtin_amdgcn_global_load_lds(                                          \
      (const __attribute__((address_space(1))) void*)(g),                    \
      (__attribute__((address_space(3))) void*)(l), 16, 0, 0)

static __device__ __forceinline__ unsigned short f2b(float f) {
  union { float f; unsigned u; } x; x.f = f;
  unsigned r = x.u + 0x7fffu + ((x.u >> 16) & 1u);
  return (unsigned short)(r >> 16);
}

// Swizzled short-offset for 64-short (128B) rows: XOR the 16B-chunk index
// with ((row ^ row>>3) & 7). Bijective within each row.
static __device__ __forceinline__ int swz8(int row, int c0) {
  return row * 64 + (((c0 ^ (row ^ (row >> 3))) & 7) * 8);
}

// ---------------- fp32 -> bf16 conversion (vectorized, optional scale) -----
__global__ __launch_bounds__(256) void conv_f2b(const float* __restrict__ in,
                                                unsigned short* __restrict__ out,
                                                int n, float scale) {
  int i = (blockIdx.x * 256 + threadIdx.x) * 4;
  const int stride = gridDim.x * 256 * 4;
  for (; i < n; i += stride) {
    float4 v = *(const float4*)(in + i);
    ushort4 o;
    o.x = f2b(v.x * scale); o.y = f2b(v.y * scale);
    o.z = f2b(v.z * scale); o.w = f2b(v.w * scale);
    *(ushort4*)(out + i) = o;
  }
}

// ---------------- GEMM: C[M,N] = A[M,K] @ W[N,K]^T + bias*bscale -----------
// 128x128 tile, BK=32, 256 threads (4 waves, 2x2). XCD-chunked bid swizzle.
template <typename OUT>
__global__ __launch_bounds__(256) void gemm_mfma(
    const unsigned short* __restrict__ A,   // [M][K] bf16
    const unsigned short* __restrict__ B,   // [N][K] bf16 (= B^T layout)
    const float* __restrict__ bias,
    OUT* __restrict__ C, int M, int N, int K, float bscale) {
  __shared__ unsigned short As[128 * 32];
  __shared__ unsigned short Bs[128 * 32];
  const int tid = threadIdx.x;
  const int lane = tid & 63;
  const int w = tid >> 6;            // 0..3
  const int wr = w >> 1, wc = w & 1; // wave grid 2x2, 64x64 each
  const int lin = blockIdx.y * gridDim.x + blockIdx.x;
  const int nwg = gridDim.x * gridDim.y;
  const int cpx = nwg >> 3;
  const int swz = (lin & 7) * cpx + (lin >> 3);
  const int brow = (swz >> 3) * 128, bcol = (swz & 7) * 128;

  f32x4 acc[4][4] = {};

  const int srow = lane >> 2;           // 0..15
  const int scol = (lane & 3) * 8;      // 0,8,16,24
  const unsigned short* Ag0 = A + (size_t)(brow + w * 16 + srow) * K + scol;
  const unsigned short* Ag1 = A + (size_t)(brow + 64 + w * 16 + srow) * K + scol;
  const unsigned short* Bg0 = B + (size_t)(bcol + w * 16 + srow) * K + scol;
  const unsigned short* Bg1 = B + (size_t)(bcol + 64 + w * 16 + srow) * K + scol;
  unsigned short* As0 = &As[(w * 16) * 32];
  unsigned short* As1 = &As[(64 + w * 16) * 32];
  unsigned short* Bs0 = &Bs[(w * 16) * 32];
  unsigned short* Bs1 = &Bs[(64 + w * 16) * 32];

  const int fr = lane & 15;        // fragment row/col
  const int k8 = (lane >> 4) * 8;  // fragment k offset

  for (int k0 = 0; k0 < K; k0 += 32) {
    GLOAD16(Ag0 + k0, As0);
    GLOAD16(Ag1 + k0, As1);
    GLOAD16(Bg0 + k0, Bs0);
    GLOAD16(Bg1 + k0, Bs1);
    __syncthreads();

    bf16x8 a[4], bb[4];
#pragma unroll
    for (int m = 0; m < 4; ++m)
      a[m] = *(const bf16x8*)&As[(wr * 64 + m * 16 + fr) * 32 + k8];
#pragma unroll
    for (int n = 0; n < 4; ++n)
      bb[n] = *(const bf16x8*)&Bs[(wc * 64 + n * 16 + fr) * 32 + k8];
#pragma unroll
    for (int m = 0; m < 4; ++m)
#pragma unroll
      for (int n = 0; n < 4; ++n)
        acc[m][n] = __builtin_amdgcn_mfma_f32_16x16x32_bf16(a[m], bb[n], acc[m][n], 0, 0, 0);
    __syncthreads();
  }

#pragma unroll
  for (int m = 0; m < 4; ++m) {
    int row = brow + wr * 64 + m * 16 + (lane >> 4) * 4;
#pragma unroll
    for (int n = 0; n < 4; ++n) {
      int col = bcol + wc * 64 + n * 16 + fr;
      float bv = bias[col] * bscale;
#pragma unroll
      for (int j = 0; j < 4; ++j) {
        float vv = acc[m][n][j] + bv;
        if constexpr (sizeof(OUT) == 2)
          ((unsigned short*)C)[(size_t)(row + j) * N + col] = f2b(vv);
        else
          ((float*)C)[(size_t)(row + j) * N + col] = vv;
      }
    }
  }
}

// ---------------- Flash attention (causal), bf16 MFMA, swizzled LDS -------
// Pair-balanced: block handles q-tiles (p, 15-p) -> uniform 34 KV-tiles/block.
// 4 waves x 32 q-rows per 128-row tile. KVBLK=64. Scores pre-scaled by
// 0.125*log2(e) (folded into Wq/bq) so softmax runs in exp2 domain directly.
__global__ __launch_bounds__(256) void attn_mfma(
    const unsigned short* __restrict__ q, const unsigned short* __restrict__ k,
    const unsigned short* __restrict__ v, unsigned short* __restrict__ ctx) {
  __shared__ unsigned short Ks[64 * 64];      // [kv][d] swizzled
  __shared__ unsigned short Vt[64 * 64];      // [d][kv] swizzled
  __shared__ unsigned short Ps[4][32 * 64];   // per-wave [qrow][kv] swizzled

  // XCD-chunked swizzle over 512 blocks: 64 consecutive per XCD; each XCD
  // covers whole (b,h) groups -> K/V tiles L2-local.
  const int orig = blockIdx.x;
  const int sbid = (orig & 7) * 64 + (orig >> 3);
  const int pair = sbid & 7;         // q-tile pair id
  const int h = (sbid >> 3) & 15;
  const int b = sbid >> 7;

  const int tid = threadIdx.x;
  const int lane = tid & 63;
  const int w = tid >> 6;

  const size_t bS = (size_t)b * SS;
  const int fr = lane & 15;
  const int qw = lane >> 4;            // quarter-wave 0..3
  const int k8 = qw * 8;

  // K staging (gload_lds): linear LDS dest + pre-swizzled global source.
  const int r0 = w * 8 + (lane >> 3);
  const int g0 = ((lane & 7) ^ (r0 ^ (r0 >> 3))) & 7;
  const int r1 = 32 + w * 8 + (lane >> 3);
  const int g1 = ((lane & 7) ^ (r1 ^ (r1 >> 3))) & 7;
  const unsigned short* Kg0 = k + (bS + r0) * DD + h * 64 + g0 * 8;
  const unsigned short* Kg1 = k + (bS + r1) * DD + h * 64 + g1 * 8;
  unsigned short* KsD0 = &Ks[(w * 8) * 64];
  unsigned short* KsD1 = &Ks[(32 + w * 8) * 64];

  for (int half = 0; half < 2; ++half) {
    const int qt = half ? (15 - pair) : pair;
    const int q0w = qt * 128 + w * 32;   // wave's first q row

    // Q fragments (A-layout): rows q0w+h2*16+fr, d = s*32+k8..+8
    bf16x8 aq[2][2];
#pragma unroll
    for (int h2 = 0; h2 < 2; ++h2) {
      const unsigned short* qrow = q + (bS + q0w + h2 * 16 + fr) * DD + h * 64;
#pragma unroll
      for (int s = 0; s < 2; ++s)
        aq[h2][s] = *(const bf16x8*)(qrow + s * 32 + k8);
    }

    f32x4 oc[2][4] = {};
    float m_run[2][4], l_run[2][4];
#pragma unroll
    for (int h2 = 0; h2 < 2; ++h2)
#pragma unroll
      for (int j = 0; j < 4; ++j) { m_run[h2][j] = -INFINITY; l_run[h2][j] = 0.0f; }

    const int nkt = qt * 2 + 2;
    for (int kt = 0; kt < nkt; ++kt) {
      __syncthreads();  // previous iteration's readers done
      const size_t koff = (size_t)(kt * 64) * DD;
      GLOAD16(Kg0 + koff, KsD0);
      GLOAD16(Kg1 + koff, KsD1);
      // V transpose staging: vector load + swizzled scalar stores
#pragma unroll
      for (int r = 0; r < 2; ++r) {
        int idx = r * 256 + tid;     // 0..511
        int kv = idx >> 3;           // 0..63
        int d0 = (idx & 7) * 8;
        bf16x8 vv = *(const bf16x8*)(v + (bS + kt * 64 + kv) * DD + h * 64 + d0);
        int ch = kv >> 3, cl = kv & 7;
#pragma unroll
        for (int j2 = 0; j2 < 8; ++j2)
          Vt[swz8(d0 + j2, ch) + cl] = ((const unsigned short*)&vv)[j2];
      }
      __syncthreads();  // tiles resident

      // S = Q K^T : 16 MFMAs (bk shared across h2). Scores already scaled.
      f32x4 sc[2][4] = {};
      __builtin_amdgcn_s_setprio(1);
#pragma unroll
      for (int n = 0; n < 4; ++n) {
        int row = n * 16 + fr;
        bf16x8 bk0 = *(const bf16x8*)&Ks[swz8(row, qw)];
        bf16x8 bk1 = *(const bf16x8*)&Ks[swz8(row, 4 + qw)];
#pragma unroll
        for (int h2 = 0; h2 < 2; ++h2) {
          sc[h2][n] = __builtin_amdgcn_mfma_f32_16x16x32_bf16(aq[h2][0], bk0, sc[h2][n], 0, 0, 0);
          sc[h2][n] = __builtin_amdgcn_mfma_f32_16x16x32_bf16(aq[h2][1], bk1, sc[h2][n], 0, 0, 0);
        }
      }
      __builtin_amdgcn_s_setprio(0);

      // causal mask only on diagonal band
      if (kt * 64 + 63 > q0w) {
#pragma unroll
        for (int h2 = 0; h2 < 2; ++h2)
#pragma unroll
          for (int n = 0; n < 4; ++n) {
            int colg = kt * 64 + n * 16 + fr;
#pragma unroll
            for (int j = 0; j < 4; ++j) {
              int rowg = q0w + h2 * 16 + qw * 4 + j;
              if (colg > rowg) sc[h2][n][j] = -1e30f;
            }
          }
      }

      // online softmax (exp2 domain). l kept as per-lane partial (deferred
      // cross-lane sum to epilogue: saves 4 shfl per row per tile).
#pragma unroll
      for (int h2 = 0; h2 < 2; ++h2) {
#pragma unroll
        for (int j = 0; j < 4; ++j) {
          float rm = fmaxf(fmaxf(sc[h2][0][j], sc[h2][1][j]),
                           fmaxf(sc[h2][2][j], sc[h2][3][j]));
#pragma unroll
          for (int off = 8; off >= 1; off >>= 1) rm = fmaxf(rm, __shfl_xor(rm, off));
          float mo = m_run[h2][j];
          float mn = fmaxf(mo, rm);
          float fac = exp2f(mo - mn);
          float p[4], rs = 0.0f;
#pragma unroll
          for (int n = 0; n < 4; ++n) { p[n] = exp2f(sc[h2][n][j] - mn); rs += p[n]; }
          l_run[h2][j] = l_run[h2][j] * fac + rs;   // per-lane partial
          m_run[h2][j] = mn;
#pragma unroll
          for (int n = 0; n < 4; ++n) oc[h2][n][j] *= fac;
          int prow = h2 * 16 + qw * 4 + j;
#pragma unroll
          for (int n = 0; n < 4; ++n)
            Ps[w][swz8(prow, n * 2 + (fr >> 3)) + (fr & 7)] = f2b(p[n]);
        }
      }

      asm volatile("s_waitcnt lgkmcnt(0)" ::: "memory");  // wave-local Ps ready

      // O += P @ V : 16 MFMAs (bv shared across h2)
      __builtin_amdgcn_s_setprio(1);
#pragma unroll
      for (int s = 0; s < 2; ++s) {
        bf16x8 pa0 = *(const bf16x8*)&Ps[w][swz8(fr, s * 4 + qw)];
        bf16x8 pa1 = *(const bf16x8*)&Ps[w][swz8(16 + fr, s * 4 + qw)];
#pragma unroll
        for (int n = 0; n < 4; ++n) {
          bf16x8 bv = *(const bf16x8*)&Vt[swz8(n * 16 + fr, s * 4 + qw)];
          oc[0][n] = __builtin_amdgcn_mfma_f32_16x16x32_bf16(pa0, bv, oc[0][n], 0, 0, 0);
          oc[1][n] = __builtin_amdgcn_mfma_f32_16x16x32_bf16(pa1, bv, oc[1][n], 0, 0, 0);
        }
      }
      __builtin_amdgcn_s_setprio(0);
    }

    // epilogue: reduce l partials across the 16-lane row group, write ctx
#pragma unroll
    for (int h2 = 0; h2 < 2; ++h2)
#pragma unroll
      for (int j = 0; j < 4; ++j) {
        float ls = l_run[h2][j];
#pragma unroll
        for (int off = 8; off >= 1; off >>= 1) ls += __shfl_xor(ls, off);
        float inv = 1.0f / ls;
        int row = q0w + h2 * 16 + qw * 4 + j;
        unsigned short* crow = ctx + (bS + row) * DD + h * 64;
#pragma unroll
        for (int n = 0; n < 4; ++n)
          crow[n * 16 + fr] = f2b(oc[h2][n][j] * inv);
      }
  }
}

extern "C" void kernel_launch(void* const* d_in, const int* in_sizes, int n_in,
                              void* d_out, int out_size, void* d_ws, size_t ws_size,
                              hipStream_t stream) {
  const float* query = (const float*)d_in[0];
  const float* key_  = (const float*)d_in[1];
  const float* value = (const float*)d_in[2];
  const float* Wq = (const float*)d_in[3];
  const float* bq = (const float*)d_in[4];
  const float* Wk = (const float*)d_in[5];
  const float* bk = (const float*)d_in[6];
  const float* Wv = (const float*)d_in[7];
  const float* bv = (const float*)d_in[8];
  const float* Wo = (const float*)d_in[9];
  const float* bo = (const float*)d_in[10];
  float* out = (float*)d_out;

  const int M = BB * SS;  // 8192
  const int N = DD;       // 1024
  const int K = DD;       // 1024
  const size_t NX = (size_t)M * DD;   // 8.4M elems
  const size_t NW = (size_t)DD * DD;  // 1M elems
  const float SCL = 0.1803368801f;    // 0.125 * log2(e), folded into Wq/bq

  unsigned short* Xb = (unsigned short*)d_ws;     // converted input / ctx (reused)
  unsigned short* W0 = Xb + NX;
  unsigned short* W1 = W0 + NW;
  unsigned short* W2 = W1 + NW;
  unsigned short* W3 = W2 + NW;
  unsigned short* qb = W3 + NW;
  unsigned short* kb = qb + NX;
  unsigned short* vb = kb + NX;

  dim3 cblk(256), cgrid(2048);
  dim3 gblk(256), ggrid(N / 128, M / 128);

  // weights once (Wq pre-scaled so attention scores land in exp2 domain)
  hipLaunchKernelGGL(conv_f2b, dim3(256), cblk, 0, stream, Wq, W0, (int)NW, SCL);
  hipLaunchKernelGGL(conv_f2b, dim3(256), cblk, 0, stream, Wk, W1, (int)NW, 1.0f);
  hipLaunchKernelGGL(conv_f2b, dim3(256), cblk, 0, stream, Wv, W2, (int)NW, 1.0f);
  hipLaunchKernelGGL(conv_f2b, dim3(256), cblk, 0, stream, Wo, W3, (int)NW, 1.0f);

  // q = query @ (Wq*SCL)^T + bq*SCL
  hipLaunchKernelGGL(conv_f2b, cgrid, cblk, 0, stream, query, Xb, (int)NX, 1.0f);
  hipLaunchKernelGGL(gemm_mfma<unsigned short>, ggrid, gblk, 0, stream,
                     Xb, W0, bq, qb, M, N, K, SCL);
  // k
  hipLaunchKernelGGL(conv_f2b, cgrid, cblk, 0, stream, key_, Xb, (int)NX, 1.0f);
  hipLaunchKernelGGL(gemm_mfma<unsigned short>, ggrid, gblk, 0, stream,
                     Xb, W1, bk, kb, M, N, K, 1.0f);
  // v
  hipLaunchKernelGGL(conv_f2b, cgrid, cblk, 0, stream, value, Xb, (int)NX, 1.0f);
  hipLaunchKernelGGL(gemm_mfma<unsigned short>, ggrid, gblk, 0, stream,
                     Xb, W2, bv, vb, M, N, K, 1.0f);

  // attention -> ctx (bf16) into Xb. 512 pair-balanced blocks.
  hipLaunchKernelGGL(attn_mfma, dim3(BB * HH * (SS / 256)), dim3(256), 0, stream,
                     qb, kb, vb, Xb);

  // out = ctx @ Wo^T + bo  (fp32 out)
  hipLaunchKernelGGL(gemm_mfma<float>, ggrid, gblk, 0, stream,
                     Xb, W3, bo, out, M, N, K, 1.0f);
}